// Round 3
// baseline (96.631 us; speedup 1.0000x reference)
//
#include <hip/hip_runtime.h>
#include <cstdint>

#define T_DIM 1024
#define O_DIM 512
#define D_DIM 256
#define H_DIM 512
#define H2_DIM 256   // packed h-pairs

typedef _Float16 f16x2 __attribute__((ext_vector_type(2)));
typedef _Float16 f16x8 __attribute__((ext_vector_type(8)));
typedef float f32x4 __attribute__((ext_vector_type(4)));

__device__ __forceinline__ uint32_t pack2(float a, float b) {
    f16x2 p;
    p.x = (_Float16)a;
    p.y = (_Float16)b;
    return __builtin_bit_cast(uint32_t, p);
}

// --- guaranteed-VOP3P packed ops -------------------------------------------
__device__ __forceinline__ uint32_t pk_add(uint32_t a, uint32_t b) {
    uint32_t d;
    asm("v_pk_add_f16 %0, %1, %2" : "=v"(d) : "v"(a), "v"(b));
    return d;
}
__device__ __forceinline__ float dot2(uint32_t a, uint32_t b, float c) {
    float d;
    asm("v_dot2_f32_f16 %0, %1, %2, %3" : "=v"(d) : "v"(a), "v"(b), "v"(c));
    return d;
}

struct u4 { uint32_t x, y, z, w; };

// ---------------- Kernel A: MFMA f16 dual GEMM -> packed transposed ws -----
// D'[n][m] = sum_k W1[k][n]*Amat[m][k] (+b1 for ht), stored as
// outT2[h2=n/2][m] = f16pair(n, n+1).
// K-loop register double-buffer: prefetch tile k+1 during MFMA on tile k.
#define GA_PAD 20   // uint32 (f16-pair) row stride: 16 kp + 4 pad

__global__ __launch_bounds__(256) void gemm_a(
    const float* __restrict__ z_t, const float* __restrict__ z_o,
    const float* __restrict__ W1, const float* __restrict__ b1,
    uint32_t* __restrict__ htT2, uint32_t* __restrict__ hoT2)
{
    const int bm = blockIdx.x;
    const int bn = blockIdx.y;
    const bool is_o = bm >= (T_DIM / 64);
    const float* Amat = is_o ? z_o : z_t;
    const int m0 = (is_o ? bm - T_DIM / 64 : bm) * 64;
    const int n0 = bn * 64;
    const int krow0 = is_o ? D_DIM : 0;
    const int Mdim = is_o ? O_DIM : T_DIM;
    uint32_t* outT2 = is_o ? hoT2 : htT2;

    __shared__ __align__(16) uint32_t lds_a[64 * GA_PAD];  // [m][kp] f16 pairs
    __shared__ __align__(16) uint32_t lds_w[64 * GA_PAD];  // [n][kp] f16 pairs

    const int tid = threadIdx.x;
    const int lane = tid & 63;
    const int wv = tid >> 6;       // wave id 0..3 -> n-slice
    const int quad = lane >> 4;
    const int l15 = lane & 15;

    f32x4 acc[4];
#pragma unroll
    for (int i = 0; i < 4; ++i) acc[i] = (f32x4)(0.0f);

    const int a_m = tid >> 2;
    const int a_kq = (tid & 3) * 8;
    const int w_kp = tid >> 4;
    const int w_nq = (tid & 15) * 4;

    // prologue: load K-tile 0 into registers
    float4 va0, va1, wa0, wa1;
    {
        const float* p = &Amat[(size_t)(m0 + a_m) * D_DIM + a_kq];
        va0 = *reinterpret_cast<const float4*>(p);
        va1 = *reinterpret_cast<const float4*>(p + 4);
        const float* r0 = &W1[(size_t)(krow0 + 2 * w_kp) * H_DIM + n0 + w_nq];
        wa0 = *reinterpret_cast<const float4*>(r0);
        wa1 = *reinterpret_cast<const float4*>(r0 + H_DIM);
    }

    for (int k0 = 0; k0 < D_DIM; k0 += 32) {
        // stage registers -> LDS
        lds_a[a_m * GA_PAD + a_kq / 2 + 0] = pack2(va0.x, va0.y);
        lds_a[a_m * GA_PAD + a_kq / 2 + 1] = pack2(va0.z, va0.w);
        lds_a[a_m * GA_PAD + a_kq / 2 + 2] = pack2(va1.x, va1.y);
        lds_a[a_m * GA_PAD + a_kq / 2 + 3] = pack2(va1.z, va1.w);
        lds_w[(w_nq + 0) * GA_PAD + w_kp] = pack2(wa0.x, wa1.x);
        lds_w[(w_nq + 1) * GA_PAD + w_kp] = pack2(wa0.y, wa1.y);
        lds_w[(w_nq + 2) * GA_PAD + w_kp] = pack2(wa0.z, wa1.z);
        lds_w[(w_nq + 3) * GA_PAD + w_kp] = pack2(wa0.w, wa1.w);
        __syncthreads();

        // prefetch next K-tile (latency hides under MFMA + barrier)
        if (k0 + 32 < D_DIM) {
            const float* p = &Amat[(size_t)(m0 + a_m) * D_DIM + k0 + 32 + a_kq];
            va0 = *reinterpret_cast<const float4*>(p);
            va1 = *reinterpret_cast<const float4*>(p + 4);
            const float* r0 =
                &W1[(size_t)(krow0 + k0 + 32 + 2 * w_kp) * H_DIM + n0 + w_nq];
            wa0 = *reinterpret_cast<const float4*>(r0);
            wa1 = *reinterpret_cast<const float4*>(r0 + H_DIM);
        }

        u4 au;
        {
            const uint32_t* s = &lds_w[(wv * 16 + l15) * GA_PAD + quad * 4];
            au.x = s[0]; au.y = s[1]; au.z = s[2]; au.w = s[3];
        }
        f16x8 afrag = __builtin_bit_cast(f16x8, au);
#pragma unroll
        for (int mi = 0; mi < 4; ++mi) {
            u4 bu;
            const uint32_t* s = &lds_a[(mi * 16 + l15) * GA_PAD + quad * 4];
            bu.x = s[0]; bu.y = s[1]; bu.z = s[2]; bu.w = s[3];
            f16x8 bfrag = __builtin_bit_cast(f16x8, bu);
            acc[mi] = __builtin_amdgcn_mfma_f32_16x16x32_f16(afrag, bfrag,
                                                             acc[mi], 0, 0, 0);
        }
        __syncthreads();
    }

    const int nbase = n0 + wv * 16 + quad * 4;
    float b0 = 0.f, b1v = 0.f, b2v = 0.f, b3v = 0.f;
    if (!is_o) {
        b0 = b1[nbase + 0]; b1v = b1[nbase + 1];
        b2v = b1[nbase + 2]; b3v = b1[nbase + 3];
    }
#pragma unroll
    for (int mi = 0; mi < 4; ++mi) {
        const int m = m0 + mi * 16 + l15;
        outT2[(size_t)((nbase >> 1) + 0) * Mdim + m] = pack2(acc[mi][0] + b0, acc[mi][1] + b1v);
        outT2[(size_t)((nbase >> 1) + 1) * Mdim + m] = pack2(acc[mi][2] + b2v, acc[mi][3] + b3v);
    }
}

// ---------------- Kernel B: single-split fused abs-dot -> OUT directly -----
// leaky(x) = 0.505x + 0.495|x|; 0.505x is rank-1 separable, computed here
// from the staged tiles.  One block owns ALL 256 h-pairs for a 64t x 32o
// output tile, so out = b2 + KLIN*(ct+co) + abs-part is written directly:
// no `part` workspace, no combine kernel.
// Inner loop: 3 ops per h-pair (v_pk_add_f16, v_and_b32, v_dot2_f32_f16).
#define RB_T 64    // t per block
#define RB_O 32    // o per block

__global__ __launch_bounds__(512) void reduce_b(
    const uint32_t* __restrict__ htT2, const uint32_t* __restrict__ hoT2,
    const float* __restrict__ W2, const float* __restrict__ b2,
    float* __restrict__ out)
{
    __shared__ __align__(16) uint32_t ht_s[H2_DIM * RB_T];  // [h2][t] 64KB
    __shared__ __align__(16) uint32_t ho_s[H2_DIM * RB_O];  // [h2][o] 32KB
    __shared__ uint32_t w2s[H2_DIM];                        // 0.495*W2 pairs
    __shared__ float red_t[8][RB_T];
    __shared__ float red_o[16][RB_O];
    __shared__ __align__(16) float ct_s[RB_T];
    __shared__ __align__(16) float co_s[RB_O];

    const int tid = threadIdx.x;
    const int t0 = blockIdx.x * RB_T;
    const int o0 = blockIdx.y * RB_O;

    if (tid < H2_DIM)
        w2s[tid] = pack2(0.495f * W2[tid * 2], 0.495f * W2[tid * 2 + 1]);

    // stage ht tile: 256 h2 x 64 t (16 uint4 per row) -> 8 passes of 512
#pragma unroll
    for (int r = 0; r < 8; ++r) {
        const int c = tid + r * 512;
        const int row = c >> 4;
        const int c4 = (c & 15) * 4;
        *reinterpret_cast<uint4*>(&ht_s[row * RB_T + c4]) =
            *reinterpret_cast<const uint4*>(
                &htT2[(size_t)row * T_DIM + t0 + c4]);
    }
    // stage ho tile: 256 h2 x 32 o (8 uint4 per row) -> 4 passes of 512
#pragma unroll
    for (int r = 0; r < 4; ++r) {
        const int c = tid + r * 512;
        const int row = c >> 3;
        const int c4 = (c & 7) * 4;
        *reinterpret_cast<uint4*>(&ho_s[row * RB_O + c4]) =
            *reinterpret_cast<const uint4*>(
                &hoT2[(size_t)row * O_DIM + o0 + c4]);
    }
    __syncthreads();

    const int og = tid & 7;    // o-group: 4 o each
    const int tg = tid >> 3;   // t: 1 each (0..63)

    float acc[4] = {};

    // h2 loop in batches of 4 with register double-buffer: 48 VALU insts of
    // cover per batch x 2 waves/SIMD ~ 192 issue cycles > ds latency.
    uint32_t a_[4], w_[4];
    uint4 b_[4];
#pragma unroll
    for (int r = 0; r < 4; ++r) {
        a_[r] = ht_s[r * RB_T + tg];
        b_[r] = *reinterpret_cast<const uint4*>(&ho_s[r * RB_O + og * 4]);
        w_[r] = w2s[r];
    }

    for (int g = 0; g < H2_DIM; g += 4) {
        const int gn = (g + 4) & (H2_DIM - 1);   // wraps to 0 on last iter
        uint32_t na_[4], nw_[4];
        uint4 nb_[4];
#pragma unroll
        for (int r = 0; r < 4; ++r) {
            na_[r] = ht_s[(gn + r) * RB_T + tg];
            nb_[r] = *reinterpret_cast<const uint4*>(
                &ho_s[(gn + r) * RB_O + og * 4]);
            nw_[r] = w2s[gn + r];
        }
#pragma unroll
        for (int r = 0; r < 4; ++r) {
            const uint32_t bv[4] = {b_[r].x, b_[r].y, b_[r].z, b_[r].w};
#pragma unroll
            for (int j = 0; j < 4; ++j) {
                const uint32_t s = pk_add(a_[r], bv[j]);   // v_pk_add_f16
                const uint32_t l = s & 0x7FFF7FFFu;        // packed |s|
                acc[j] = dot2(l, w_[r], acc[j]);           // v_dot2_f32_f16
            }
        }
#pragma unroll
        for (int r = 0; r < 4; ++r) { a_[r] = na_[r]; b_[r] = nb_[r]; w_[r] = nw_[r]; }
    }

    // rank-1 partials from the staged tiles (0.495*W2 folded in w2s)
    {
        const int t = tid & 63, slc = tid >> 6;          // 8 slices x 32 h2
        float s = 0.f;
#pragma unroll 8
        for (int j = 0; j < 32; ++j)
            s = dot2(ht_s[(slc * 32 + j) * RB_T + t], w2s[slc * 32 + j], s);
        red_t[slc][t] = s;
        const int o = tid & 31, slo = tid >> 5;          // 16 slices x 16 h2
        float so = 0.f;
#pragma unroll 8
        for (int j = 0; j < 16; ++j)
            so = dot2(ho_s[(slo * 16 + j) * RB_O + o], w2s[slo * 16 + j], so);
        red_o[slo][o] = so;
    }
    __syncthreads();
    if (tid < RB_T) {
        float s = 0.f;
#pragma unroll
        for (int j = 0; j < 8; ++j) s += red_t[j][tid];
        ct_s[tid] = s;
    } else if (tid < RB_T + RB_O) {
        const int o = tid - RB_T;
        float s = 0.f;
#pragma unroll
        for (int j = 0; j < 16; ++j) s += red_o[j][o];
        co_s[o] = s;
    }
    __syncthreads();

    const float KLIN = 0.505f / 0.495f;
    const float base = b2[0] + KLIN * ct_s[tg];
    const float4 cov = *reinterpret_cast<const float4*>(&co_s[og * 4]);
    float4 v;
    v.x = base + KLIN * cov.x + acc[0];
    v.y = base + KLIN * cov.y + acc[1];
    v.z = base + KLIN * cov.z + acc[2];
    v.w = base + KLIN * cov.w + acc[3];
    *reinterpret_cast<float4*>(
        &out[(size_t)(t0 + tg) * O_DIM + o0 + og * 4]) = v;
}

extern "C" void kernel_launch(void* const* d_in, const int* in_sizes, int n_in,
                              void* d_out, int out_size, void* d_ws, size_t ws_size,
                              hipStream_t stream) {
    const float* z_t = (const float*)d_in[0];
    const float* z_o = (const float*)d_in[1];
    const float* W1  = (const float*)d_in[2];
    const float* b1  = (const float*)d_in[3];
    const float* W2  = (const float*)d_in[4];
    const float* b2  = (const float*)d_in[5];
    float* out = (float*)d_out;

    // ws layout: htT2 1MB @0 | hoT2 0.5MB @0x100000  (1.5MB total)
    char* wsb = (char*)d_ws;
    uint32_t* htT2 = (uint32_t*)(wsb);
    uint32_t* hoT2 = (uint32_t*)(wsb + 0x100000);

    dim3 gridA((T_DIM + O_DIM) / 64, H_DIM / 64);        // (24, 8)
    gemm_a<<<gridA, 256, 0, stream>>>(z_t, z_o, W1, b1, htT2, hoT2);

    dim3 gridB(T_DIM / RB_T, O_DIM / RB_O);              // (16, 16) = 256 blocks
    reduce_b<<<gridB, 512, 0, stream>>>(htT2, hoT2, W2, b2, out);
}

// Round 4
// 94.104 us; speedup vs baseline: 1.0269x; 1.0269x over previous
//
#include <hip/hip_runtime.h>
#include <cstdint>

#define T_DIM 1024
#define O_DIM 512
#define D_DIM 256
#define H_DIM 512
#define H2_DIM 256   // packed h-pairs

typedef _Float16 f16x2 __attribute__((ext_vector_type(2)));
typedef _Float16 f16x8 __attribute__((ext_vector_type(8)));
typedef float f32x4 __attribute__((ext_vector_type(4)));

__device__ __forceinline__ uint32_t pack2(float a, float b) {
    f16x2 p;
    p.x = (_Float16)a;
    p.y = (_Float16)b;
    return __builtin_bit_cast(uint32_t, p);
}

// --- guaranteed-VOP3P packed ops -------------------------------------------
__device__ __forceinline__ uint32_t pk_add(uint32_t a, uint32_t b) {
    uint32_t d;
    asm("v_pk_add_f16 %0, %1, %2" : "=v"(d) : "v"(a), "v"(b));
    return d;
}
__device__ __forceinline__ float dot2(uint32_t a, uint32_t b, float c) {
    float d;
    asm("v_dot2_f32_f16 %0, %1, %2, %3" : "=v"(d) : "v"(a), "v"(b), "v"(c));
    return d;
}

struct u4 { uint32_t x, y, z, w; };

// ---------------- Kernel A: MFMA f16 dual GEMM -> packed transposed ws -----
// D'[n][m] = sum_k W1[k][n]*Amat[m][k] (+b1 for ht), stored as
// outT2[h2=n/2][m] = f16pair(n, n+1).
// K-loop register double-buffer: prefetch tile k+1 during MFMA on tile k.
#define GA_PAD 20   // uint32 (f16-pair) row stride: 16 kp + 4 pad

__global__ __launch_bounds__(256) void gemm_a(
    const float* __restrict__ z_t, const float* __restrict__ z_o,
    const float* __restrict__ W1, const float* __restrict__ b1,
    uint32_t* __restrict__ htT2, uint32_t* __restrict__ hoT2)
{
    const int bm = blockIdx.x;
    const int bn = blockIdx.y;
    const bool is_o = bm >= (T_DIM / 64);
    const float* Amat = is_o ? z_o : z_t;
    const int m0 = (is_o ? bm - T_DIM / 64 : bm) * 64;
    const int n0 = bn * 64;
    const int krow0 = is_o ? D_DIM : 0;
    const int Mdim = is_o ? O_DIM : T_DIM;
    uint32_t* outT2 = is_o ? hoT2 : htT2;

    __shared__ __align__(16) uint32_t lds_a[64 * GA_PAD];  // [m][kp] f16 pairs
    __shared__ __align__(16) uint32_t lds_w[64 * GA_PAD];  // [n][kp] f16 pairs

    const int tid = threadIdx.x;
    const int lane = tid & 63;
    const int wv = tid >> 6;       // wave id 0..3 -> n-slice
    const int quad = lane >> 4;
    const int l15 = lane & 15;

    f32x4 acc[4];
#pragma unroll
    for (int i = 0; i < 4; ++i) acc[i] = (f32x4)(0.0f);

    const int a_m = tid >> 2;
    const int a_kq = (tid & 3) * 8;
    const int w_kp = tid >> 4;
    const int w_nq = (tid & 15) * 4;

    // prologue: load K-tile 0 into registers
    float4 va0, va1, wa0, wa1;
    {
        const float* p = &Amat[(size_t)(m0 + a_m) * D_DIM + a_kq];
        va0 = *reinterpret_cast<const float4*>(p);
        va1 = *reinterpret_cast<const float4*>(p + 4);
        const float* r0 = &W1[(size_t)(krow0 + 2 * w_kp) * H_DIM + n0 + w_nq];
        wa0 = *reinterpret_cast<const float4*>(r0);
        wa1 = *reinterpret_cast<const float4*>(r0 + H_DIM);
    }

    for (int k0 = 0; k0 < D_DIM; k0 += 32) {
        // stage registers -> LDS
        lds_a[a_m * GA_PAD + a_kq / 2 + 0] = pack2(va0.x, va0.y);
        lds_a[a_m * GA_PAD + a_kq / 2 + 1] = pack2(va0.z, va0.w);
        lds_a[a_m * GA_PAD + a_kq / 2 + 2] = pack2(va1.x, va1.y);
        lds_a[a_m * GA_PAD + a_kq / 2 + 3] = pack2(va1.z, va1.w);
        lds_w[(w_nq + 0) * GA_PAD + w_kp] = pack2(wa0.x, wa1.x);
        lds_w[(w_nq + 1) * GA_PAD + w_kp] = pack2(wa0.y, wa1.y);
        lds_w[(w_nq + 2) * GA_PAD + w_kp] = pack2(wa0.z, wa1.z);
        lds_w[(w_nq + 3) * GA_PAD + w_kp] = pack2(wa0.w, wa1.w);
        __syncthreads();

        // prefetch next K-tile (latency hides under MFMA + barrier)
        if (k0 + 32 < D_DIM) {
            const float* p = &Amat[(size_t)(m0 + a_m) * D_DIM + k0 + 32 + a_kq];
            va0 = *reinterpret_cast<const float4*>(p);
            va1 = *reinterpret_cast<const float4*>(p + 4);
            const float* r0 =
                &W1[(size_t)(krow0 + k0 + 32 + 2 * w_kp) * H_DIM + n0 + w_nq];
            wa0 = *reinterpret_cast<const float4*>(r0);
            wa1 = *reinterpret_cast<const float4*>(r0 + H_DIM);
        }

        u4 au;
        {
            const uint32_t* s = &lds_w[(wv * 16 + l15) * GA_PAD + quad * 4];
            au.x = s[0]; au.y = s[1]; au.z = s[2]; au.w = s[3];
        }
        f16x8 afrag = __builtin_bit_cast(f16x8, au);
#pragma unroll
        for (int mi = 0; mi < 4; ++mi) {
            u4 bu;
            const uint32_t* s = &lds_a[(mi * 16 + l15) * GA_PAD + quad * 4];
            bu.x = s[0]; bu.y = s[1]; bu.z = s[2]; bu.w = s[3];
            f16x8 bfrag = __builtin_bit_cast(f16x8, bu);
            acc[mi] = __builtin_amdgcn_mfma_f32_16x16x32_f16(afrag, bfrag,
                                                             acc[mi], 0, 0, 0);
        }
        __syncthreads();
    }

    const int nbase = n0 + wv * 16 + quad * 4;
    float b0 = 0.f, b1v = 0.f, b2v = 0.f, b3v = 0.f;
    if (!is_o) {
        b0 = b1[nbase + 0]; b1v = b1[nbase + 1];
        b2v = b1[nbase + 2]; b3v = b1[nbase + 3];
    }
#pragma unroll
    for (int mi = 0; mi < 4; ++mi) {
        const int m = m0 + mi * 16 + l15;
        outT2[(size_t)((nbase >> 1) + 0) * Mdim + m] = pack2(acc[mi][0] + b0, acc[mi][1] + b1v);
        outT2[(size_t)((nbase >> 1) + 1) * Mdim + m] = pack2(acc[mi][2] + b2v, acc[mi][3] + b3v);
    }
}

// ---------------- Kernel B: fused abs-dot, 2-way h-split partials ----------
// leaky(x) = 0.505x + 0.495|x|; 0.505x is rank-1 separable ->
//   sum_h W2[h]*0.505*(ht+ho) = (0.505/0.495)*(ctp[t] + cop[o])
// (w2s carries 0.495*W2).  |x| part: 3 ops per h-pair
// (v_pk_add_f16, v_and_b32, v_dot2_f32_f16); 16 accs/thread keeps the
// inner-loop issue density at 48 VALU per 3 ds_read (round-3 lesson).
#define RB_T 64    // t per block
#define RB_O 64    // o per block
#define RB_H2 128  // h2 pairs per block -> 2 splits

__global__ __launch_bounds__(256) void reduce_b(
    const uint32_t* __restrict__ htT2, const uint32_t* __restrict__ hoT2,
    const float* __restrict__ W2, float* __restrict__ part,
    float* __restrict__ ctp, float* __restrict__ cop)
{
    __shared__ __align__(16) uint32_t ht_s[RB_H2 * RB_T];  // [h2][t] 32KB
    __shared__ __align__(16) uint32_t ho_s[RB_H2 * RB_O];  // [h2][o] 32KB
    __shared__ uint32_t w2s[RB_H2];                        // 0.495*W2 pairs
    __shared__ float red_t[4][RB_T];
    __shared__ float red_o[4][RB_O];

    const int tid = threadIdx.x;
    const int t0 = blockIdx.x * RB_T;
    const int o0 = blockIdx.y * RB_O;
    const int h2b = blockIdx.z * RB_H2;

    if (tid < RB_H2)
        w2s[tid] = pack2(0.495f * W2[(h2b + tid) * 2],
                         0.495f * W2[(h2b + tid) * 2 + 1]);

    // stage ht tile: 128 h2 x 64 t = 2048 uint4 -> 8 passes of 256
#pragma unroll
    for (int r = 0; r < 8; ++r) {
        const int c = tid + r * 256;
        const int row = c >> 4;
        const int c4 = (c & 15) * 4;
        *reinterpret_cast<uint4*>(&ht_s[row * RB_T + c4]) =
            *reinterpret_cast<const uint4*>(
                &htT2[(size_t)(h2b + row) * T_DIM + t0 + c4]);
    }
    // stage ho tile: 128 h2 x 64 o
#pragma unroll
    for (int r = 0; r < 8; ++r) {
        const int c = tid + r * 256;
        const int row = c >> 4;
        const int c4 = (c & 15) * 4;
        *reinterpret_cast<uint4*>(&ho_s[row * RB_O + c4]) =
            *reinterpret_cast<const uint4*>(
                &hoT2[(size_t)(h2b + row) * O_DIM + o0 + c4]);
    }
    __syncthreads();

    const int og = tid & 15;   // o-group: 4 o each
    const int tg = tid >> 4;   // t-group: 4 t each

    float acc[4][4] = {};

    // h2 loop in batches of 2 with register double-buffer:
    // 96 VALU of cover per 6 ds_read (~192 issue cyc > ds latency).
    uint4 a_[2], b_[2];
    uint32_t w_[2];
#pragma unroll
    for (int r = 0; r < 2; ++r) {
        a_[r] = *reinterpret_cast<const uint4*>(&ht_s[r * RB_T + tg * 4]);
        b_[r] = *reinterpret_cast<const uint4*>(&ho_s[r * RB_O + og * 4]);
        w_[r] = w2s[r];
    }

    for (int g = 0; g < RB_H2; g += 2) {
        const int gn = (g + 2) & (RB_H2 - 1);   // wraps to 0 on last iter
        uint4 na_[2], nb_[2];
        uint32_t nw_[2];
#pragma unroll
        for (int r = 0; r < 2; ++r) {
            na_[r] = *reinterpret_cast<const uint4*>(
                &ht_s[(gn + r) * RB_T + tg * 4]);
            nb_[r] = *reinterpret_cast<const uint4*>(
                &ho_s[(gn + r) * RB_O + og * 4]);
            nw_[r] = w2s[gn + r];
        }
#pragma unroll
        for (int r = 0; r < 2; ++r) {
            const uint32_t av[4] = {a_[r].x, a_[r].y, a_[r].z, a_[r].w};
            const uint32_t bv[4] = {b_[r].x, b_[r].y, b_[r].z, b_[r].w};
#pragma unroll
            for (int i = 0; i < 4; ++i)
#pragma unroll
                for (int j = 0; j < 4; ++j) {
                    const uint32_t s = pk_add(av[i], bv[j]);   // v_pk_add_f16
                    const uint32_t l = s & 0x7FFF7FFFu;        // packed |s|
                    acc[i][j] = dot2(l, w_[r], acc[i][j]);     // v_dot2_f32_f16
                }
        }
#pragma unroll
        for (int r = 0; r < 2; ++r) { a_[r] = na_[r]; b_[r] = nb_[r]; w_[r] = nw_[r]; }
    }

    float* p = part + (size_t)blockIdx.z * T_DIM * O_DIM;
#pragma unroll
    for (int i = 0; i < 4; ++i) {
        float4 v = make_float4(acc[i][0], acc[i][1], acc[i][2], acc[i][3]);
        *reinterpret_cast<float4*>(
            &p[(size_t)(t0 + tg * 4 + i) * O_DIM + o0 + og * 4]) = v;
    }

    // rank-1 partials from the staged tiles (0.495*W2 folded in w2s).
    // Duplicate writes across the other grid axis are bitwise identical.
    {
        const int t = tid & 63, slc = tid >> 6;          // 4 slices x 32 h2
        float s = 0.f;
#pragma unroll 8
        for (int j = 0; j < 32; ++j)
            s = dot2(ht_s[(slc * 32 + j) * RB_T + t], w2s[slc * 32 + j], s);
        red_t[slc][t] = s;
        float so = 0.f;
#pragma unroll 8
        for (int j = 0; j < 32; ++j)
            so = dot2(ho_s[(slc * 32 + j) * RB_O + t], w2s[slc * 32 + j], so);
        red_o[slc][t] = so;
    }
    __syncthreads();
    if (tid < RB_T) {
        ctp[(size_t)blockIdx.z * T_DIM + t0 + tid] =
            red_t[0][tid] + red_t[1][tid] + red_t[2][tid] + red_t[3][tid];
    } else if (tid < RB_T + RB_O) {
        const int o = tid - RB_T;
        cop[(size_t)blockIdx.z * O_DIM + o0 + o] =
            red_o[0][o] + red_o[1][o] + red_o[2][o] + red_o[3][o];
    }
}

// ---------------- Kernel C: combine ----------------------------------------
// out = b2 + sum_{hs=0,1} part[hs] + (0.505/0.495)*(ct[t] + co[o])
__global__ __launch_bounds__(256) void combine(
    const float* __restrict__ part, const float* __restrict__ ctp,
    const float* __restrict__ cop, const float* __restrict__ b2,
    float* __restrict__ out)
{
    const float bb = b2[0];
    const float KLIN = 0.505f / 0.495f;
    const int Q = T_DIM * O_DIM / 4;
    const float4* cop4 = reinterpret_cast<const float4*>(cop);
    const float4* p4 = reinterpret_cast<const float4*>(part);
#pragma unroll
    for (int r = 0; r < 2; ++r) {
        const int idx = blockIdx.x * 512 + r * 256 + threadIdx.x;
        const int t = idx >> 7;          // 128 float4 per t-row
        const int oc = idx & 127;
        const float ct = ctp[t] + ctp[T_DIM + t];
        float4 co = cop4[oc];
        const float4 c1 = cop4[128 + oc];
        co.x += c1.x; co.y += c1.y; co.z += c1.z; co.w += c1.w;
        const float4 s0 = p4[idx];
        const float4 s1 = p4[idx + Q];
        const float base = bb + KLIN * ct;
        float4 o;
        o.x = base + KLIN * co.x + (s0.x + s1.x);
        o.y = base + KLIN * co.y + (s0.y + s1.y);
        o.z = base + KLIN * co.z + (s0.z + s1.z);
        o.w = base + KLIN * co.w + (s0.w + s1.w);
        reinterpret_cast<float4*>(out)[idx] = o;
    }
}

extern "C" void kernel_launch(void* const* d_in, const int* in_sizes, int n_in,
                              void* d_out, int out_size, void* d_ws, size_t ws_size,
                              hipStream_t stream) {
    const float* z_t = (const float*)d_in[0];
    const float* z_o = (const float*)d_in[1];
    const float* W1  = (const float*)d_in[2];
    const float* b1  = (const float*)d_in[3];
    const float* W2  = (const float*)d_in[4];
    const float* b2  = (const float*)d_in[5];
    float* out = (float*)d_out;

    // ws layout (max usage 6MB, within previously verified 10MB):
    // htT2 1MB @0 | hoT2 0.5MB @0x100000 | ctp 8KB @0x180000 |
    // cop 4KB @0x184000 | part 2x2MB @0x200000 (ends 0x600000)
    char* wsb = (char*)d_ws;
    uint32_t* htT2 = (uint32_t*)(wsb);
    uint32_t* hoT2 = (uint32_t*)(wsb + 0x100000);
    float* ctp     = (float*)(wsb + 0x180000);
    float* cop     = (float*)(wsb + 0x184000);
    float* part    = (float*)(wsb + 0x200000);

    dim3 gridA((T_DIM + O_DIM) / 64, H_DIM / 64);        // (24, 8)
    gemm_a<<<gridA, 256, 0, stream>>>(z_t, z_o, W1, b1, htT2, hoT2);

    dim3 gridB(T_DIM / RB_T, O_DIM / RB_O, H2_DIM / RB_H2);  // (16, 8, 2)
    reduce_b<<<gridB, 256, 0, stream>>>(htT2, hoT2, W2, part, ctp, cop);

    combine<<<T_DIM * O_DIM / (4 * 512), 256, 0, stream>>>(part, ctp, cop, b2, out);
}

// Round 5
// 92.424 us; speedup vs baseline: 1.0455x; 1.0182x over previous
//
#include <hip/hip_runtime.h>
#include <cstdint>

#define T_DIM 1024
#define O_DIM 512
#define D_DIM 256
#define H_DIM 512
#define H2_DIM 256   // packed h-pairs

typedef _Float16 f16x2 __attribute__((ext_vector_type(2)));
typedef _Float16 f16x8 __attribute__((ext_vector_type(8)));
typedef float f32x4 __attribute__((ext_vector_type(4)));

__device__ __forceinline__ uint32_t pack2(float a, float b) {
    f16x2 p;
    p.x = (_Float16)a;
    p.y = (_Float16)b;
    return __builtin_bit_cast(uint32_t, p);
}

// --- guaranteed-VOP3P packed ops -------------------------------------------
__device__ __forceinline__ uint32_t pk_add(uint32_t a, uint32_t b) {
    uint32_t d;
    asm("v_pk_add_f16 %0, %1, %2" : "=v"(d) : "v"(a), "v"(b));
    return d;
}
__device__ __forceinline__ float dot2(uint32_t a, uint32_t b, float c) {
    float d;
    asm("v_dot2_f32_f16 %0, %1, %2, %3" : "=v"(d) : "v"(a), "v"(b), "v"(c));
    return d;
}

struct u4 { uint32_t x, y, z, w; };

// ---------------- Kernel A: MFMA f16 dual GEMM -> packed transposed ws -----
// D'[n][m] = sum_k W1[k][n]*Amat[m][k] (+b1 for ht), stored as
// outT2[h2=n/2][m] = f16pair(n, n+1).
// K-step 64 (4 iters, 8 barriers vs 16) + register double-buffer.
// MFMA sequence identical to K=32 version -> bit-identical output.
#define GA_PAD 36   // uint32 (f16-pair) row stride: 32 kp + 4 pad

__global__ __launch_bounds__(256) void gemm_a(
    const float* __restrict__ z_t, const float* __restrict__ z_o,
    const float* __restrict__ W1, const float* __restrict__ b1,
    uint32_t* __restrict__ htT2, uint32_t* __restrict__ hoT2)
{
    const int bm = blockIdx.x;
    const int bn = blockIdx.y;
    const bool is_o = bm >= (T_DIM / 64);
    const float* Amat = is_o ? z_o : z_t;
    const int m0 = (is_o ? bm - T_DIM / 64 : bm) * 64;
    const int n0 = bn * 64;
    const int krow0 = is_o ? D_DIM : 0;
    const int Mdim = is_o ? O_DIM : T_DIM;
    uint32_t* outT2 = is_o ? hoT2 : htT2;

    __shared__ __align__(16) uint32_t lds_a[64 * GA_PAD];  // [m][kp] 9.2KB
    __shared__ __align__(16) uint32_t lds_w[64 * GA_PAD];  // [n][kp] 9.2KB

    const int tid = threadIdx.x;
    const int lane = tid & 63;
    const int wv = tid >> 6;       // wave id 0..3 -> n-slice
    const int quad = lane >> 4;
    const int l15 = lane & 15;

    f32x4 acc[4];
#pragma unroll
    for (int i = 0; i < 4; ++i) acc[i] = (f32x4)(0.0f);

    const int a_m = tid >> 2;             // 4 threads per m-row
    const int a_kq = (tid & 3) * 16;      // 16 floats (8 kp) each
    const int w_kp0 = tid >> 4;           // kp 0..15 (+16 on pass 2)
    const int w_nq = (tid & 15) * 4;

    // prologue: load K-tile 0 into registers
    float4 va[4], wr0[2], wr1[2];
    {
        const float* pa = &Amat[(size_t)(m0 + a_m) * D_DIM + a_kq];
#pragma unroll
        for (int q = 0; q < 4; ++q)
            va[q] = *reinterpret_cast<const float4*>(pa + q * 4);
#pragma unroll
        for (int p2 = 0; p2 < 2; ++p2) {
            const int k = krow0 + 2 * (w_kp0 + p2 * 16);
            wr0[p2] = *reinterpret_cast<const float4*>(
                &W1[(size_t)k * H_DIM + n0 + w_nq]);
            wr1[p2] = *reinterpret_cast<const float4*>(
                &W1[(size_t)(k + 1) * H_DIM + n0 + w_nq]);
        }
    }

    for (int k0 = 0; k0 < D_DIM; k0 += 64) {
        // stage registers -> LDS
#pragma unroll
        for (int q = 0; q < 4; ++q) {
            lds_a[a_m * GA_PAD + a_kq / 2 + q * 2 + 0] = pack2(va[q].x, va[q].y);
            lds_a[a_m * GA_PAD + a_kq / 2 + q * 2 + 1] = pack2(va[q].z, va[q].w);
        }
#pragma unroll
        for (int p2 = 0; p2 < 2; ++p2) {
            const int kp = w_kp0 + p2 * 16;
            lds_w[(w_nq + 0) * GA_PAD + kp] = pack2(wr0[p2].x, wr1[p2].x);
            lds_w[(w_nq + 1) * GA_PAD + kp] = pack2(wr0[p2].y, wr1[p2].y);
            lds_w[(w_nq + 2) * GA_PAD + kp] = pack2(wr0[p2].z, wr1[p2].z);
            lds_w[(w_nq + 3) * GA_PAD + kp] = pack2(wr0[p2].w, wr1[p2].w);
        }
        __syncthreads();

        // prefetch next K-tile (latency hides under MFMA + barrier)
        if (k0 + 64 < D_DIM) {
            const float* pa = &Amat[(size_t)(m0 + a_m) * D_DIM + k0 + 64 + a_kq];
#pragma unroll
            for (int q = 0; q < 4; ++q)
                va[q] = *reinterpret_cast<const float4*>(pa + q * 4);
#pragma unroll
            for (int p2 = 0; p2 < 2; ++p2) {
                const int k = krow0 + k0 + 64 + 2 * (w_kp0 + p2 * 16);
                wr0[p2] = *reinterpret_cast<const float4*>(
                    &W1[(size_t)k * H_DIM + n0 + w_nq]);
                wr1[p2] = *reinterpret_cast<const float4*>(
                    &W1[(size_t)(k + 1) * H_DIM + n0 + w_nq]);
            }
        }

        // 2 k-subtiles of 32 per staged tile
#pragma unroll
        for (int ks = 0; ks < 2; ++ks) {
            u4 au;
            {
                const uint32_t* s =
                    &lds_w[(wv * 16 + l15) * GA_PAD + ks * 16 + quad * 4];
                au.x = s[0]; au.y = s[1]; au.z = s[2]; au.w = s[3];
            }
            f16x8 afrag = __builtin_bit_cast(f16x8, au);
#pragma unroll
            for (int mi = 0; mi < 4; ++mi) {
                u4 bu;
                const uint32_t* s =
                    &lds_a[(mi * 16 + l15) * GA_PAD + ks * 16 + quad * 4];
                bu.x = s[0]; bu.y = s[1]; bu.z = s[2]; bu.w = s[3];
                f16x8 bfrag = __builtin_bit_cast(f16x8, bu);
                acc[mi] = __builtin_amdgcn_mfma_f32_16x16x32_f16(
                    afrag, bfrag, acc[mi], 0, 0, 0);
            }
        }
        __syncthreads();
    }

    const int nbase = n0 + wv * 16 + quad * 4;
    float b0 = 0.f, b1v = 0.f, b2v = 0.f, b3v = 0.f;
    if (!is_o) {
        b0 = b1[nbase + 0]; b1v = b1[nbase + 1];
        b2v = b1[nbase + 2]; b3v = b1[nbase + 3];
    }
#pragma unroll
    for (int mi = 0; mi < 4; ++mi) {
        const int m = m0 + mi * 16 + l15;
        outT2[(size_t)((nbase >> 1) + 0) * Mdim + m] = pack2(acc[mi][0] + b0, acc[mi][1] + b1v);
        outT2[(size_t)((nbase >> 1) + 1) * Mdim + m] = pack2(acc[mi][2] + b2v, acc[mi][3] + b3v);
    }
}

// ---------------- Kernel B: fused abs-dot, 2-way h-split partials ----------
// leaky(x) = 0.505x + 0.495|x|; 0.505x is rank-1 separable ->
//   sum_h W2[h]*0.505*(ht+ho) = (0.505/0.495)*(ctp[t] + cop[o])
// (w2s carries 0.495*W2).  |x| part: 3 ops per h-pair
// (v_pk_add_f16, v_and_b32, v_dot2_f32_f16); 16 accs/thread keeps the
// inner-loop issue density at 48 VALU per 3 ds_read (round-3 lesson).
#define RB_T 64    // t per block
#define RB_O 64    // o per block
#define RB_H2 128  // h2 pairs per block -> 2 splits

__global__ __launch_bounds__(256) void reduce_b(
    const uint32_t* __restrict__ htT2, const uint32_t* __restrict__ hoT2,
    const float* __restrict__ W2, float* __restrict__ part,
    float* __restrict__ ctp, float* __restrict__ cop)
{
    __shared__ __align__(16) uint32_t ht_s[RB_H2 * RB_T];  // [h2][t] 32KB
    __shared__ __align__(16) uint32_t ho_s[RB_H2 * RB_O];  // [h2][o] 32KB
    __shared__ uint32_t w2s[RB_H2];                        // 0.495*W2 pairs
    __shared__ float red_t[4][RB_T];
    __shared__ float red_o[4][RB_O];

    const int tid = threadIdx.x;
    const int t0 = blockIdx.x * RB_T;
    const int o0 = blockIdx.y * RB_O;
    const int h2b = blockIdx.z * RB_H2;

    if (tid < RB_H2)
        w2s[tid] = pack2(0.495f * W2[(h2b + tid) * 2],
                         0.495f * W2[(h2b + tid) * 2 + 1]);

    // stage ht tile: 128 h2 x 64 t = 2048 uint4 -> 8 passes of 256
#pragma unroll
    for (int r = 0; r < 8; ++r) {
        const int c = tid + r * 256;
        const int row = c >> 4;
        const int c4 = (c & 15) * 4;
        *reinterpret_cast<uint4*>(&ht_s[row * RB_T + c4]) =
            *reinterpret_cast<const uint4*>(
                &htT2[(size_t)(h2b + row) * T_DIM + t0 + c4]);
    }
    // stage ho tile: 128 h2 x 64 o
#pragma unroll
    for (int r = 0; r < 8; ++r) {
        const int c = tid + r * 256;
        const int row = c >> 4;
        const int c4 = (c & 15) * 4;
        *reinterpret_cast<uint4*>(&ho_s[row * RB_O + c4]) =
            *reinterpret_cast<const uint4*>(
                &hoT2[(size_t)(h2b + row) * O_DIM + o0 + c4]);
    }
    __syncthreads();

    const int og = tid & 15;   // o-group: 4 o each
    const int tg = tid >> 4;   // t-group: 4 t each

    float acc[4][4] = {};

    // h2 loop in batches of 2 with register double-buffer:
    // 96 VALU of cover per 6 ds_read (~192 issue cyc > ds latency).
    uint4 a_[2], b_[2];
    uint32_t w_[2];
#pragma unroll
    for (int r = 0; r < 2; ++r) {
        a_[r] = *reinterpret_cast<const uint4*>(&ht_s[r * RB_T + tg * 4]);
        b_[r] = *reinterpret_cast<const uint4*>(&ho_s[r * RB_O + og * 4]);
        w_[r] = w2s[r];
    }

    for (int g = 0; g < RB_H2; g += 2) {
        const int gn = (g + 2) & (RB_H2 - 1);   // wraps to 0 on last iter
        uint4 na_[2], nb_[2];
        uint32_t nw_[2];
#pragma unroll
        for (int r = 0; r < 2; ++r) {
            na_[r] = *reinterpret_cast<const uint4*>(
                &ht_s[(gn + r) * RB_T + tg * 4]);
            nb_[r] = *reinterpret_cast<const uint4*>(
                &ho_s[(gn + r) * RB_O + og * 4]);
            nw_[r] = w2s[gn + r];
        }
#pragma unroll
        for (int r = 0; r < 2; ++r) {
            const uint32_t av[4] = {a_[r].x, a_[r].y, a_[r].z, a_[r].w};
            const uint32_t bv[4] = {b_[r].x, b_[r].y, b_[r].z, b_[r].w};
#pragma unroll
            for (int i = 0; i < 4; ++i)
#pragma unroll
                for (int j = 0; j < 4; ++j) {
                    const uint32_t s = pk_add(av[i], bv[j]);   // v_pk_add_f16
                    const uint32_t l = s & 0x7FFF7FFFu;        // packed |s|
                    acc[i][j] = dot2(l, w_[r], acc[i][j]);     // v_dot2_f32_f16
                }
        }
#pragma unroll
        for (int r = 0; r < 2; ++r) { a_[r] = na_[r]; b_[r] = nb_[r]; w_[r] = nw_[r]; }
    }

    float* p = part + (size_t)blockIdx.z * T_DIM * O_DIM;
#pragma unroll
    for (int i = 0; i < 4; ++i) {
        float4 v = make_float4(acc[i][0], acc[i][1], acc[i][2], acc[i][3]);
        *reinterpret_cast<float4*>(
            &p[(size_t)(t0 + tg * 4 + i) * O_DIM + o0 + og * 4]) = v;
    }

    // rank-1 partials from the staged tiles (0.495*W2 folded in w2s).
    // Duplicate writes across the other grid axis are bitwise identical.
    {
        const int t = tid & 63, slc = tid >> 6;          // 4 slices x 32 h2
        float s = 0.f;
#pragma unroll 8
        for (int j = 0; j < 32; ++j)
            s = dot2(ht_s[(slc * 32 + j) * RB_T + t], w2s[slc * 32 + j], s);
        red_t[slc][t] = s;
        float so = 0.f;
#pragma unroll 8
        for (int j = 0; j < 32; ++j)
            so = dot2(ho_s[(slc * 32 + j) * RB_O + t], w2s[slc * 32 + j], so);
        red_o[slc][t] = so;
    }
    __syncthreads();
    if (tid < RB_T) {
        ctp[(size_t)blockIdx.z * T_DIM + t0 + tid] =
            red_t[0][tid] + red_t[1][tid] + red_t[2][tid] + red_t[3][tid];
    } else if (tid < RB_T + RB_O) {
        const int o = tid - RB_T;
        cop[(size_t)blockIdx.z * O_DIM + o0 + o] =
            red_o[0][o] + red_o[1][o] + red_o[2][o] + red_o[3][o];
    }
}

// ---------------- Kernel C: combine ----------------------------------------
// out = b2 + sum_{hs=0,1} part[hs] + (0.505/0.495)*(ct[t] + co[o])
__global__ __launch_bounds__(256) void combine(
    const float* __restrict__ part, const float* __restrict__ ctp,
    const float* __restrict__ cop, const float* __restrict__ b2,
    float* __restrict__ out)
{
    const float bb = b2[0];
    const float KLIN = 0.505f / 0.495f;
    const int Q = T_DIM * O_DIM / 4;
    const float4* cop4 = reinterpret_cast<const float4*>(cop);
    const float4* p4 = reinterpret_cast<const float4*>(part);
#pragma unroll
    for (int r = 0; r < 2; ++r) {
        const int idx = blockIdx.x * 512 + r * 256 + threadIdx.x;
        const int t = idx >> 7;          // 128 float4 per t-row
        const int oc = idx & 127;
        const float ct = ctp[t] + ctp[T_DIM + t];
        float4 co = cop4[oc];
        const float4 c1 = cop4[128 + oc];
        co.x += c1.x; co.y += c1.y; co.z += c1.z; co.w += c1.w;
        const float4 s0 = p4[idx];
        const float4 s1 = p4[idx + Q];
        const float base = bb + KLIN * ct;
        float4 o;
        o.x = base + KLIN * co.x + (s0.x + s1.x);
        o.y = base + KLIN * co.y + (s0.y + s1.y);
        o.z = base + KLIN * co.z + (s0.z + s1.z);
        o.w = base + KLIN * co.w + (s0.w + s1.w);
        reinterpret_cast<float4*>(out)[idx] = o;
    }
}

extern "C" void kernel_launch(void* const* d_in, const int* in_sizes, int n_in,
                              void* d_out, int out_size, void* d_ws, size_t ws_size,
                              hipStream_t stream) {
    const float* z_t = (const float*)d_in[0];
    const float* z_o = (const float*)d_in[1];
    const float* W1  = (const float*)d_in[2];
    const float* b1  = (const float*)d_in[3];
    const float* W2  = (const float*)d_in[4];
    const float* b2  = (const float*)d_in[5];
    float* out = (float*)d_out;

    // ws layout (max usage 6MB, within previously verified 10MB):
    // htT2 1MB @0 | hoT2 0.5MB @0x100000 | ctp 8KB @0x180000 |
    // cop 4KB @0x184000 | part 2x2MB @0x200000 (ends 0x600000)
    char* wsb = (char*)d_ws;
    uint32_t* htT2 = (uint32_t*)(wsb);
    uint32_t* hoT2 = (uint32_t*)(wsb + 0x100000);
    float* ctp     = (float*)(wsb + 0x180000);
    float* cop     = (float*)(wsb + 0x184000);
    float* part    = (float*)(wsb + 0x200000);

    dim3 gridA((T_DIM + O_DIM) / 64, H_DIM / 64);        // (24, 8)
    gemm_a<<<gridA, 256, 0, stream>>>(z_t, z_o, W1, b1, htT2, hoT2);

    dim3 gridB(T_DIM / RB_T, O_DIM / RB_O, H2_DIM / RB_H2);  // (16, 8, 2)
    reduce_b<<<gridB, 256, 0, stream>>>(htT2, hoT2, W2, part, ctp, cop);

    combine<<<T_DIM * O_DIM / (4 * 512), 256, 0, stream>>>(part, ctp, cop, b2, out);
}